// Round 15
// baseline (268.338 us; speedup 1.0000x reference)
//
#include <hip/hip_runtime.h>
#include <hip/hip_bf16.h>
#include <stdint.h>

#define IN_CH 794
#define KPAD  832            // 13 * 64
#define Z1C   1024
#define OUT_C 512
#define BATCH 32768

typedef __attribute__((ext_vector_type(8))) short short8;
typedef __attribute__((ext_vector_type(4))) float f32x4;

__device__ __forceinline__ ushort f2bf(float f) {
  uint32_t u = __float_as_uint(f);
  return (ushort)((u + 0x7fffu + ((u >> 16) & 1u)) >> 16);  // RTNE
}

__device__ __forceinline__ void glds16(const void* g, void* l) {
  __builtin_amdgcn_global_load_lds(
      (const __attribute__((address_space(1))) void*)g,
      (__attribute__((address_space(3))) void*)l, 16, 0, 0);
}

#define BAR() __builtin_amdgcn_s_barrier()
#define MFMA(a, b, c) __builtin_amdgcn_mfma_f32_16x16x32_bf16(a, b, c, 0, 0, 0)

// ------- prepx: masked weights + folded bias + (flag-gated) x conversion -------
__global__ __launch_bounds__(256) void prepx(
    const float* __restrict__ W1, const float* __restrict__ b1,
    const float* __restrict__ Wc1, const float* __restrict__ bc1,
    const float* __restrict__ MW0, ushort* __restrict__ w1p,
    float* __restrict__ bias1, const float* __restrict__ W2,
    const float* __restrict__ b2, const float* __restrict__ Wc2,
    const float* __restrict__ bc2, const float* __restrict__ MW1,
    ushort* __restrict__ w2m, float* __restrict__ bias2,
    const float* __restrict__ x, ushort* __restrict__ xb, int do_x) {
  const int t = threadIdx.x;
  __shared__ float red[4];
  if (blockIdx.x < 1024) {
    const int z = blockIdx.x;
    float sum = 0.f;
    for (int i = t; i < KPAD; i += 256) {
      float w = 0.f;
      if (i < IN_CH) {
        float m = MW0[z * IN_CH + i];
        w = W1[z * IN_CH + i] * m;
        sum += Wc1[z * IN_CH + i] * m;
      }
      w1p[z * KPAD + i] = f2bf(w);
    }
#pragma unroll
    for (int o = 32; o > 0; o >>= 1) sum += __shfl_down(sum, o, 64);
    if ((t & 63) == 0) red[t >> 6] = sum;
    __syncthreads();
    if (t == 0) bias1[z] = b1[z] + bc1[z] + red[0] + red[1] + red[2] + red[3];
  } else if (blockIdx.x < 1536) {
    const int z = blockIdx.x - 1024;
    float sum = 0.f;
    for (int i = t; i < Z1C; i += 256) {
      float m = MW1[z * Z1C + i];
      w2m[z * Z1C + i] = f2bf(W2[z * Z1C + i] * m);
      sum += Wc2[z * Z1C + i] * m;
    }
#pragma unroll
    for (int o = 32; o > 0; o >>= 1) sum += __shfl_down(sum, o, 64);
    if ((t & 63) == 0) red[t >> 6] = sum;
    __syncthreads();
    if (t == 0) bias2[z] = b2[z] + bc2[z] + red[0] + red[1] + red[2] + red[3];
  } else {
    if (!do_x) return;
    const int CPR = KPAD / 8;                 // 104
    const int total = BATCH * CPR;
    for (int i = (blockIdx.x - 1536) * 256 + t; i < total; i += 2048 * 256) {
      int row = i / CPR;
      int col = (i - row * CPR) * 8;
      const float* p = x + (size_t)row * IN_CH + col;
      ushort u[8];
      if (col + 8 <= IN_CH) {
#pragma unroll
        for (int j = 0; j < 4; ++j) {
          float2 v = *(const float2*)(p + j * 2);
          u[j * 2] = f2bf(v.x);
          u[j * 2 + 1] = f2bf(v.y);
        }
      } else {
#pragma unroll
        for (int j = 0; j < 8; ++j) u[j] = (col + j < IN_CH) ? f2bf(p[j]) : 0;
      }
      *(uint4*)(xb + (size_t)row * KPAD + col) = *(uint4*)u;
    }
  }
}

// =============== gemm1_k: one round, 2 col-halves, full re-prologue ===============
// 256 blocks (1/CU), 512 thr (8 waves 2Mx4N). Block = 256 rows x 512-col pair;
// c2 in {0,1} picks the 256-col half. Body per half = r13's proven gemmT
// verbatim (A triple / B double, 4-phase counted vmcnt, LT bf16 epilogue).
// Minimal cross-half live state (pair/brow/gAp only) to stay spill-free.
__global__ __launch_bounds__(512, 2) void gemm1_k(
    const ushort* __restrict__ Ag, const ushort* __restrict__ Bg,
    const float* __restrict__ bias, ushort* __restrict__ h1) {
  __shared__ uint4 ldsq[10240];        // 163840 B
  char* const L = (char*)ldsq;         // A bufs: 3 x 32 KB
  char* const LB = L + 98304;          // B bufs: 2 x 32 KB
  const int tid = threadIdx.x;
  const int lane = tid & 63, wid = tid >> 6;
  const int wr = wid >> 2, wc = wid & 3;

  const int nwg = gridDim.x;           // 256
  const int w0 = blockIdx.x;
  const int swz = (w0 & 7) * (nwg >> 3) + (w0 >> 3);
  const int pair = swz & 1;
  const int brow = (swz >> 1) * 256;

  const int srow = tid >> 3;
  const int scol = ((tid & 7) * 16) ^ ((srow & 7) << 4);
  const char* gAp = (const char*)Ag + (size_t)(brow + srow) * 1664 + scol;
  const int ldst = wid * 1024;

  const int rA = lane & 15;
  const int klo = (lane >> 4) * 16;
  const int xs = (rA & 7) << 4;

  auto stA = [&](int buf, int kt, int h) {
    glds16(gAp + (size_t)h * (64 * 1664) + (size_t)kt * 128,
           L + buf * 32768 + h * 8192 + ldst);
  };
  auto rdA = [&](const char* Ab, int m, int ks) -> short8 {
    int row = wr * 128 + m * 16 + rA;
    return *(const short8*)(Ab + row * 128 + ((ks * 64 + klo) ^ xs));
  };
  auto rdB = [&](const char* Bb, int n, int ks) -> short8 {
    int row = wc * 64 + n * 16 + rA;
    return *(const short8*)(Bb + row * 128 + ((ks * 64 + klo) ^ xs));
  };

#pragma unroll 1
  for (int c2 = 0; c2 < 2; ++c2) {
    const int bcol = pair * 512 + c2 * 256;
    const char* gBp = (const char*)Bg + (size_t)(bcol + srow) * 1664 + scol;
    auto stB = [&](int buf, int kt, int h) {
      glds16(gBp + (size_t)h * (64 * 1664) + (size_t)kt * 128,
             LB + buf * 32768 + h * 8192 + ldst);
    };

    // full prologue each half (half-1 A is L2/L3-hot)
#pragma unroll
    for (int h = 0; h < 4; ++h) stA(0, 0, h);
#pragma unroll
    for (int h = 0; h < 4; ++h) stB(0, 0, h);
#pragma unroll
    for (int h = 0; h < 4; ++h) stA(1, 1, h);
    asm volatile("s_waitcnt vmcnt(4)" ::: "memory");
    BAR();

    f32x4 acc[8][4] = {};

    for (int j = 0; j < 13; ++j) {
      const char* Ab = L + (j % 3) * 32768;
      const char* Bb = LB + (j & 1) * 32768;
      const int jn = j + 1, ja = j + 2;
      const int bb1 = jn & 1, ab2 = ja % 3;
      short8 aF[4][2], bF[4][2];

#pragma unroll
      for (int m = 0; m < 4; ++m) {
        aF[m][0] = rdA(Ab, m, 0); aF[m][1] = rdA(Ab, m, 1);
      }
#pragma unroll
      for (int n = 0; n < 2; ++n) {
        bF[n][0] = rdB(Bb, n, 0); bF[n][1] = rdB(Bb, n, 1);
      }
      if (jn < 13) { stB(bb1, jn, 0); stB(bb1, jn, 1); }
      BAR();
      __builtin_amdgcn_s_setprio(1);
#pragma unroll
      for (int ks = 0; ks < 2; ++ks)
#pragma unroll
        for (int m = 0; m < 4; ++m)
#pragma unroll
          for (int n = 0; n < 2; ++n)
            acc[m][n] = MFMA(aF[m][ks], bF[n][ks], acc[m][n]);
      __builtin_amdgcn_s_setprio(0);
      BAR();

#pragma unroll
      for (int n = 2; n < 4; ++n) {
        bF[n][0] = rdB(Bb, n, 0); bF[n][1] = rdB(Bb, n, 1);
      }
      if (jn < 13) { stB(bb1, jn, 2); stB(bb1, jn, 3); }
      BAR();
      __builtin_amdgcn_s_setprio(1);
#pragma unroll
      for (int ks = 0; ks < 2; ++ks)
#pragma unroll
        for (int m = 0; m < 4; ++m)
#pragma unroll
          for (int n = 2; n < 4; ++n)
            acc[m][n] = MFMA(aF[m][ks], bF[n][ks], acc[m][n]);
      __builtin_amdgcn_s_setprio(0);
      BAR();

#pragma unroll
      for (int m = 0; m < 4; ++m) {
        aF[m][0] = rdA(Ab, m + 4, 0); aF[m][1] = rdA(Ab, m + 4, 1);
      }
      if (ja < 13) { stA(ab2, ja, 0); stA(ab2, ja, 1); }
      BAR();
      __builtin_amdgcn_s_setprio(1);
#pragma unroll
      for (int ks = 0; ks < 2; ++ks)
#pragma unroll
        for (int m = 0; m < 4; ++m)
#pragma unroll
          for (int n = 0; n < 2; ++n)
            acc[m + 4][n] = MFMA(aF[m][ks], bF[n][ks], acc[m + 4][n]);
      __builtin_amdgcn_s_setprio(0);
      BAR();

      if (ja < 13) { stA(ab2, ja, 2); stA(ab2, ja, 3); }
      BAR();
      __builtin_amdgcn_s_setprio(1);
#pragma unroll
      for (int ks = 0; ks < 2; ++ks)
#pragma unroll
        for (int m = 0; m < 4; ++m)
#pragma unroll
          for (int n = 2; n < 4; ++n)
            acc[m + 4][n] = MFMA(aF[m][ks], bF[n][ks], acc[m + 4][n]);
      __builtin_amdgcn_s_setprio(0);
      if (ja < 13)
        asm volatile("s_waitcnt vmcnt(4)" ::: "memory");
      else if (jn < 13)
        asm volatile("s_waitcnt vmcnt(0)" ::: "memory");
      BAR();
    }

    // ---- r13-proven LDS-restaged coalesced bf16 epilogue ----
    char* const LT = (char*)ldsq;  // 64 KB [128][512B]
#pragma unroll
    for (int h = 0; h < 2; ++h) {
      if (wr == h) {
#pragma unroll
        for (int n = 0; n < 4; ++n) {
          const int col = wc * 64 + n * 16 + rA;
          const float bv = bias[bcol + col];
#pragma unroll
          for (int m = 0; m < 8; ++m)
#pragma unroll
            for (int r = 0; r < 4; ++r) {
              const int R = m * 16 + (lane >> 4) * 4 + r;
              float v = acc[m][n][r] + bv;
              v = v > 0.f ? v : 0.f;
              *(ushort*)(LT + R * 512 + ((col * 2) ^ ((R & 7) << 4))) = f2bf(v);
            }
        }
      }
      __syncthreads();
#pragma unroll
      for (int it = 0; it < 8; ++it) {
        const int idx = it * 8192 + tid * 16;
        const int R = idx >> 9, cb = idx & 511;
        uint4 v = *(const uint4*)(LT + R * 512 + (cb ^ ((R & 7) << 4)));
        *(uint4*)((char*)h1 + (size_t)(brow + h * 128 + R) * 2048 + bcol * 2 +
                  cb) = v;
      }
      __syncthreads();   // also isolates epilogue reads from next prologue
    }
  }
}

// ======== gemmT (r5/r13-proven): used for GEMM2 (f32 out) ========
template <int KP, int NKT, int NCB, int OSTR>
__global__ __launch_bounds__(512, 2) void gemmT(
    const ushort* __restrict__ Ag, const ushort* __restrict__ Bg,
    const float* __restrict__ bias, float* __restrict__ Cout) {
  __shared__ uint4 ldsq[10240];        // 163840 B
  char* const L = (char*)ldsq;
  char* const LB = L + 98304;
  const int tid = threadIdx.x;
  const int lane = tid & 63, wid = tid >> 6;
  const int wr = wid >> 2, wc = wid & 3;

  const int nwg = gridDim.x;
  const int w0 = blockIdx.x;
  const int swz = (w0 & 7) * (nwg >> 3) + (w0 >> 3);
  const int bcol = (swz % NCB) * 256;
  const int brow = (swz / NCB) * 256;

  const int srow = tid >> 3;
  const int scol = ((tid & 7) * 16) ^ ((srow & 7) << 4);
  const char* gAp = (const char*)Ag + (size_t)(brow + srow) * (KP * 2) + scol;
  const char* gBp = (const char*)Bg + (size_t)(bcol + srow) * (KP * 2) + scol;
  const int ldst = wid * 1024;

  auto stA = [&](int buf, int kt, int h) {
    glds16(gAp + (size_t)h * (64 * KP * 2) + (size_t)kt * 128,
           L + buf * 32768 + h * 8192 + ldst);
  };
  auto stB = [&](int buf, int kt, int h) {
    glds16(gBp + (size_t)h * (64 * KP * 2) + (size_t)kt * 128,
           LB + buf * 32768 + h * 8192 + ldst);
  };

  const int rA = lane & 15;
  const int klo = (lane >> 4) * 16;
  const int xs = (rA & 7) << 4;
  auto rdA = [&](const char* Ab, int m, int ks) -> short8 {
    int row = wr * 128 + m * 16 + rA;
    return *(const short8*)(Ab + row * 128 + ((ks * 64 + klo) ^ xs));
  };
  auto rdB = [&](const char* Bb, int n, int ks) -> short8 {
    int row = wc * 64 + n * 16 + rA;
    return *(const short8*)(Bb + row * 128 + ((ks * 64 + klo) ^ xs));
  };

  f32x4 acc[8][4] = {};

#pragma unroll
  for (int h = 0; h < 4; ++h) stA(0, 0, h);
#pragma unroll
  for (int h = 0; h < 4; ++h) stB(0, 0, h);
#pragma unroll
  for (int h = 0; h < 4; ++h) stA(1, 1, h);
  asm volatile("s_waitcnt vmcnt(4)" ::: "memory");
  BAR();

  for (int j = 0; j < NKT; ++j) {
    const char* Ab = L + (j % 3) * 32768;
    const char* Bb = LB + (j & 1) * 32768;
    const int jn = j + 1, ja = j + 2;
    const int bb1 = jn & 1, ab2 = ja % 3;
    short8 aF[4][2], bF[4][2];

#pragma unroll
    for (int m = 0; m < 4; ++m) {
      aF[m][0] = rdA(Ab, m, 0); aF[m][1] = rdA(Ab, m, 1);
    }
#pragma unroll
    for (int n = 0; n < 2; ++n) {
      bF[n][0] = rdB(Bb, n, 0); bF[n][1] = rdB(Bb, n, 1);
    }
    if (jn < NKT) { stB(bb1, jn, 0); stB(bb1, jn, 1); }
    BAR();
    __builtin_amdgcn_s_setprio(1);
#pragma unroll
    for (int ks = 0; ks < 2; ++ks)
#pragma unroll
      for (int m = 0; m < 4; ++m)
#pragma unroll
        for (int n = 0; n < 2; ++n)
          acc[m][n] = MFMA(aF[m][ks], bF[n][ks], acc[m][n]);
    __builtin_amdgcn_s_setprio(0);
    BAR();

#pragma unroll
    for (int n = 2; n < 4; ++n) {
      bF[n][0] = rdB(Bb, n, 0); bF[n][1] = rdB(Bb, n, 1);
    }
    if (jn < NKT) { stB(bb1, jn, 2); stB(bb1, jn, 3); }
    BAR();
    __builtin_amdgcn_s_setprio(1);
#pragma unroll
    for (int ks = 0; ks < 2; ++ks)
#pragma unroll
      for (int m = 0; m < 4; ++m)
#pragma unroll
        for (int n = 2; n < 4; ++n)
          acc[m][n] = MFMA(aF[m][ks], bF[n][ks], acc[m][n]);
    __builtin_amdgcn_s_setprio(0);
    BAR();

#pragma unroll
    for (int m = 0; m < 4; ++m) {
      aF[m][0] = rdA(Ab, m + 4, 0); aF[m][1] = rdA(Ab, m + 4, 1);
    }
    if (ja < NKT) { stA(ab2, ja, 0); stA(ab2, ja, 1); }
    BAR();
    __builtin_amdgcn_s_setprio(1);
#pragma unroll
    for (int ks = 0; ks < 2; ++ks)
#pragma unroll
      for (int m = 0; m < 4; ++m)
#pragma unroll
        for (int n = 0; n < 2; ++n)
          acc[m + 4][n] = MFMA(aF[m][ks], bF[n][ks], acc[m + 4][n]);
    __builtin_amdgcn_s_setprio(0);
    BAR();

    if (ja < NKT) { stA(ab2, ja, 2); stA(ab2, ja, 3); }
    BAR();
    __builtin_amdgcn_s_setprio(1);
#pragma unroll
    for (int ks = 0; ks < 2; ++ks)
#pragma unroll
      for (int m = 0; m < 4; ++m)
#pragma unroll
        for (int n = 2; n < 4; ++n)
          acc[m + 4][n] = MFMA(aF[m][ks], bF[n][ks], acc[m + 4][n]);
    __builtin_amdgcn_s_setprio(0);
    if (ja < NKT)
      asm volatile("s_waitcnt vmcnt(4)" ::: "memory");
    else if (jn < NKT)
      asm volatile("s_waitcnt vmcnt(0)" ::: "memory");
    BAR();
  }

#pragma unroll
  for (int n = 0; n < 4; ++n) {
    const int col = bcol + wc * 64 + n * 16 + rA;
    const float bv = bias[col];
#pragma unroll
    for (int m = 0; m < 8; ++m) {
#pragma unroll
      for (int r = 0; r < 4; ++r) {
        const int row = brow + wr * 128 + m * 16 + (lane >> 4) * 4 + r;
        float v = acc[m][n][r] + bv;
        v = v > 0.f ? v : 0.f;
        Cout[(size_t)row * OSTR + col] = v;
      }
    }
  }
}

// ---------------- GEMM1 fallback (fused conversion, round-1 proven) ----------------
__global__ __launch_bounds__(256, 2) void gemm1_fused(
    const float* __restrict__ x, const ushort* __restrict__ w1p,
    const float* __restrict__ bias1, ushort* __restrict__ h1) {
  __shared__ ushort As[128 * 32];
  __shared__ ushort Bs[128 * 32];
  const int tid = threadIdx.x;
  const int lane = tid & 63, wid = tid >> 6;
  const int wr = wid >> 1, wc = wid & 1;
  const int brow = blockIdx.x * 128;
  const int bcol = blockIdx.y * 128;
  f32x4 acc[4][4] = {};
  const int arow = tid >> 1;
  const int acol0 = (tid & 1) * 16;
  const float* xrow = x + (size_t)(brow + arow) * IN_CH;
  for (int kt = 0; kt < 26; ++kt) {
    const int k0 = kt * 32;
#pragma unroll
    for (int c = 0; c < 2; ++c) {
      int idx16 = (wid * 2 + c) * 64 + lane;
      int row = idx16 >> 2, chunk = idx16 & 3;
      glds16(w1p + (size_t)(bcol + row) * KPAD + k0 + chunk * 8,
             (char*)Bs + (wid * 2 + c) * 1024);
    }
    union { ushort u[16]; uint4 q[2]; } pk;
    if (kt < 24) {
      const float* p = xrow + k0 + acol0;
#pragma unroll
      for (int j = 0; j < 8; ++j) {
        float2 v = *(const float2*)(p + j * 2);
        pk.u[j * 2] = f2bf(v.x);
        pk.u[j * 2 + 1] = f2bf(v.y);
      }
    } else {
#pragma unroll
      for (int j = 0; j < 16; ++j) {
        int col = k0 + acol0 + j;
        pk.u[j] = f2bf(col < IN_CH ? xrow[col] : 0.f);
      }
    }
    *(uint4*)&As[arow * 32 + acol0] = pk.q[0];
    *(uint4*)&As[arow * 32 + acol0 + 8] = pk.q[1];
    __syncthreads();
    const int kb = (lane >> 4) * 8, rA = lane & 15;
    short8 af[4], bfrag[4];
#pragma unroll
    for (int m = 0; m < 4; ++m)
      af[m] = *(const short8*)&As[(wr * 64 + m * 16 + rA) * 32 + kb];
#pragma unroll
    for (int n = 0; n < 4; ++n)
      bfrag[n] = *(const short8*)&Bs[(wc * 64 + n * 16 + rA) * 32 + kb];
#pragma unroll
    for (int m = 0; m < 4; ++m)
#pragma unroll
      for (int n = 0; n < 4; ++n)
        acc[m][n] = MFMA(af[m], bfrag[n], acc[m][n]);
    __syncthreads();
  }
  const int orow0 = brow + wr * 64;
  const int ocol0 = bcol + wc * 64;
#pragma unroll
  for (int n = 0; n < 4; ++n) {
    int col = ocol0 + n * 16 + (lane & 15);
    float bv = bias1[col];
#pragma unroll
    for (int m = 0; m < 4; ++m)
#pragma unroll
      for (int r = 0; r < 4; ++r) {
        int row = orow0 + m * 16 + (lane >> 4) * 4 + r;
        float v = acc[m][n][r] + bv;
        v = v > 0.f ? v : 0.f;
        h1[(size_t)row * Z1C + col] = f2bf(v);
      }
  }
}

extern "C" void kernel_launch(void* const* d_in, const int* in_sizes, int n_in,
                              void* d_out, int out_size, void* d_ws, size_t ws_size,
                              hipStream_t stream) {
  (void)in_sizes; (void)n_in; (void)out_size;
  const float* x   = (const float*)d_in[0];
  const float* W1  = (const float*)d_in[1];
  const float* b1  = (const float*)d_in[2];
  const float* Wc1 = (const float*)d_in[3];
  const float* bc1 = (const float*)d_in[4];
  const float* W2  = (const float*)d_in[5];
  const float* b2  = (const float*)d_in[6];
  const float* Wc2 = (const float*)d_in[7];
  const float* bc2 = (const float*)d_in[8];
  const float* MW0 = (const float*)d_in[9];
  const float* MW1 = (const float*)d_in[10];

  char* ws = (char*)d_ws;
  ushort* w1p   = (ushort*)ws;                   // 1024*832*2 = 1,703,936
  ushort* w2m   = (ushort*)(ws + 1703936);       //  512*1024*2 = 1,048,576
  float*  bias1 = (float*)(ws + 2752512);        // 4096
  float*  bias2 = (float*)(ws + 2756608);        // 2048
  ushort* xb    = (ushort*)(ws + 2758656);       // 32768*832*2 = 54,525,952
  const size_t WS_NEED = 2758656ull + 54525952ull;
  const int do_x = (ws_size >= WS_NEED) ? 1 : 0;

  ushort* h1 = (ushort*)d_out;   // 32768x1024 bf16 aliases 32768x512 f32
  float*  out = (float*)d_out;

  prepx<<<3584, 256, 0, stream>>>(W1, b1, Wc1, bc1, MW0, w1p, bias1,
                                  W2, b2, Wc2, bc2, MW1, w2m, bias2,
                                  x, xb, do_x);

  if (do_x) {
    gemm1_k<<<256, 512, 0, stream>>>(xb, w1p, bias1, h1);
  } else {
    gemm1_fused<<<dim3(256, 8), 256, 0, stream>>>(x, w1p, bias1, h1);
  }
  gemmT<Z1C, 16, 2, OUT_C><<<256, 512, 0, stream>>>(h1, w2m, bias2, out);
}

// Round 16
// 129.914 us; speedup vs baseline: 2.0655x; 2.0655x over previous
//
#include <hip/hip_runtime.h>
#include <hip/hip_bf16.h>
#include <stdint.h>

#define IN_CH 794
#define KPAD  832            // 13 * 64
#define Z1C   1024
#define OUT_C 512
#define BATCH 32768

typedef __attribute__((ext_vector_type(8))) short short8;
typedef __attribute__((ext_vector_type(4))) float f32x4;

__device__ __forceinline__ ushort f2bf(float f) {
  uint32_t u = __float_as_uint(f);
  return (ushort)((u + 0x7fffu + ((u >> 16) & 1u)) >> 16);  // RTNE
}

__device__ __forceinline__ void glds16(const void* g, void* l) {
  __builtin_amdgcn_global_load_lds(
      (const __attribute__((address_space(1))) void*)g,
      (__attribute__((address_space(3))) void*)l, 16, 0, 0);
}

#define BAR() __builtin_amdgcn_s_barrier()
#define MFMA(a, b, c) __builtin_amdgcn_mfma_f32_16x16x32_bf16(a, b, c, 0, 0, 0)

// ------- prepx: masked weights + folded bias + (flag-gated) x conversion -------
// 3584 blocks: [0,1024) w1p+bias1, [1024,1536) w2m+bias2, [1536,3584) xcvt.
// All three sections independent -> weight prep hides under the xcvt wave.
__global__ __launch_bounds__(256) void prepx(
    const float* __restrict__ W1, const float* __restrict__ b1,
    const float* __restrict__ Wc1, const float* __restrict__ bc1,
    const float* __restrict__ MW0, ushort* __restrict__ w1p,
    float* __restrict__ bias1, const float* __restrict__ W2,
    const float* __restrict__ b2, const float* __restrict__ Wc2,
    const float* __restrict__ bc2, const float* __restrict__ MW1,
    ushort* __restrict__ w2m, float* __restrict__ bias2,
    const float* __restrict__ x, ushort* __restrict__ xb, int do_x) {
  const int t = threadIdx.x;
  __shared__ float red[4];
  if (blockIdx.x < 1024) {
    const int z = blockIdx.x;
    float sum = 0.f;
    for (int i = t; i < KPAD; i += 256) {
      float w = 0.f;
      if (i < IN_CH) {
        float m = MW0[z * IN_CH + i];
        w = W1[z * IN_CH + i] * m;
        sum += Wc1[z * IN_CH + i] * m;
      }
      w1p[z * KPAD + i] = f2bf(w);
    }
#pragma unroll
    for (int o = 32; o > 0; o >>= 1) sum += __shfl_down(sum, o, 64);
    if ((t & 63) == 0) red[t >> 6] = sum;
    __syncthreads();
    if (t == 0) bias1[z] = b1[z] + bc1[z] + red[0] + red[1] + red[2] + red[3];
  } else if (blockIdx.x < 1536) {
    const int z = blockIdx.x - 1024;
    float sum = 0.f;
    for (int i = t; i < Z1C; i += 256) {
      float m = MW1[z * Z1C + i];
      w2m[z * Z1C + i] = f2bf(W2[z * Z1C + i] * m);
      sum += Wc2[z * Z1C + i] * m;
    }
#pragma unroll
    for (int o = 32; o > 0; o >>= 1) sum += __shfl_down(sum, o, 64);
    if ((t & 63) == 0) red[t >> 6] = sum;
    __syncthreads();
    if (t == 0) bias2[z] = b2[z] + bc2[z] + red[0] + red[1] + red[2] + red[3];
  } else {
    if (!do_x) return;
    const int CPR = KPAD / 8;                 // 104
    const int total = BATCH * CPR;
    for (int i = (blockIdx.x - 1536) * 256 + t; i < total; i += 2048 * 256) {
      int row = i / CPR;
      int col = (i - row * CPR) * 8;
      const float* p = x + (size_t)row * IN_CH + col;
      ushort u[8];
      if (col + 8 <= IN_CH) {
#pragma unroll
        for (int j = 0; j < 4; ++j) {
          float2 v = *(const float2*)(p + j * 2);
          u[j * 2] = f2bf(v.x);
          u[j * 2 + 1] = f2bf(v.y);
        }
      } else {
#pragma unroll
        for (int j = 0; j < 8; ++j) u[j] = (col + j < IN_CH) ? f2bf(p[j]) : 0;
      }
      *(uint4*)(xb + (size_t)row * KPAD + col) = *(uint4*)u;
    }
  }
}

// ======== 256x256 4-phase pipelined GEMM (r13-proven, byte-identical) ========
// A triple-buffered / B double, counted vmcnt; BF16OUT uses the LDS-restaged
// coalesced epilogue (WRITE amplification fix, verified r13: WRITE=65536KiB).
// NOTE (r14/r15): do NOT wrap this body in an outer loop — liveness ~240 of
// the 256-reg/wave cap (8-wave block); any added loop state spills to scratch.
template <int KP, int NKT, int NCB, int OSTR, bool BF16OUT>
__global__ __launch_bounds__(512, 2) void gemmT(
    const ushort* __restrict__ Ag, const ushort* __restrict__ Bg,
    const float* __restrict__ bias, void* __restrict__ Cout) {
  __shared__ uint4 ldsq[10240];        // 163840 B
  char* const L = (char*)ldsq;         // A bufs: 3 x 32 KB
  char* const LB = L + 98304;          // B bufs: 2 x 32 KB
  const int tid = threadIdx.x;
  const int lane = tid & 63, wid = tid >> 6;
  const int wr = wid >> 2, wc = wid & 3;      // 2M x 4N

  // T1: bijective XCD chunk swizzle (nwg % 8 == 0)
  const int nwg = gridDim.x;
  const int w0 = blockIdx.x;
  const int swz = (w0 & 7) * (nwg >> 3) + (w0 >> 3);
  const int bcol = (swz % NCB) * 256;
  const int brow = (swz / NCB) * 256;

  // staging source (pre-swizzled global, rule #21)
  const int srow = tid >> 3;                   // 0..63
  const int scol = ((tid & 7) * 16) ^ ((srow & 7) << 4);
  const char* gAp = (const char*)Ag + (size_t)(brow + srow) * (KP * 2) + scol;
  const char* gBp = (const char*)Bg + (size_t)(bcol + srow) * (KP * 2) + scol;
  const int ldst = wid * 1024;

  auto stA = [&](int buf, int kt, int h) {
    glds16(gAp + (size_t)h * (64 * KP * 2) + (size_t)kt * 128,
           L + buf * 32768 + h * 8192 + ldst);
  };
  auto stB = [&](int buf, int kt, int h) {
    glds16(gBp + (size_t)h * (64 * KP * 2) + (size_t)kt * 128,
           LB + buf * 32768 + h * 8192 + ldst);
  };

  // fragment reads (swizzled ds_read_b128)
  const int rA = lane & 15;
  const int klo = (lane >> 4) * 16;
  const int xs = (rA & 7) << 4;
  auto rdA = [&](const char* Ab, int m, int ks) -> short8 {
    int row = wr * 128 + m * 16 + rA;
    return *(const short8*)(Ab + row * 128 + ((ks * 64 + klo) ^ xs));
  };
  auto rdB = [&](const char* Bb, int n, int ks) -> short8 {
    int row = wc * 64 + n * 16 + rA;
    return *(const short8*)(Bb + row * 128 + ((ks * 64 + klo) ^ xs));
  };

  f32x4 acc[8][4] = {};

  // prologue
#pragma unroll
  for (int h = 0; h < 4; ++h) stA(0, 0, h);
#pragma unroll
  for (int h = 0; h < 4; ++h) stB(0, 0, h);
#pragma unroll
  for (int h = 0; h < 4; ++h) stA(1, 1, h);
  asm volatile("s_waitcnt vmcnt(4)" ::: "memory");
  BAR();

  for (int j = 0; j < NKT; ++j) {
    const char* Ab = L + (j % 3) * 32768;
    const char* Bb = LB + (j & 1) * 32768;
    const int jn = j + 1, ja = j + 2;
    const int bb1 = jn & 1, ab2 = ja % 3;
    short8 aF[4][2], bF[4][2];

    // ---- phase 0 ----
#pragma unroll
    for (int m = 0; m < 4; ++m) {
      aF[m][0] = rdA(Ab, m, 0); aF[m][1] = rdA(Ab, m, 1);
    }
#pragma unroll
    for (int n = 0; n < 2; ++n) {
      bF[n][0] = rdB(Bb, n, 0); bF[n][1] = rdB(Bb, n, 1);
    }
    if (jn < NKT) { stB(bb1, jn, 0); stB(bb1, jn, 1); }
    BAR();
    __builtin_amdgcn_s_setprio(1);
#pragma unroll
    for (int ks = 0; ks < 2; ++ks)
#pragma unroll
      for (int m = 0; m < 4; ++m)
#pragma unroll
        for (int n = 0; n < 2; ++n)
          acc[m][n] = MFMA(aF[m][ks], bF[n][ks], acc[m][n]);
    __builtin_amdgcn_s_setprio(0);
    BAR();

    // ---- phase 1 ----
#pragma unroll
    for (int n = 2; n < 4; ++n) {
      bF[n][0] = rdB(Bb, n, 0); bF[n][1] = rdB(Bb, n, 1);
    }
    if (jn < NKT) { stB(bb1, jn, 2); stB(bb1, jn, 3); }
    BAR();
    __builtin_amdgcn_s_setprio(1);
#pragma unroll
    for (int ks = 0; ks < 2; ++ks)
#pragma unroll
      for (int m = 0; m < 4; ++m)
#pragma unroll
        for (int n = 2; n < 4; ++n)
          acc[m][n] = MFMA(aF[m][ks], bF[n][ks], acc[m][n]);
    __builtin_amdgcn_s_setprio(0);
    BAR();

    // ---- phase 2 ----
#pragma unroll
    for (int m = 0; m < 4; ++m) {
      aF[m][0] = rdA(Ab, m + 4, 0); aF[m][1] = rdA(Ab, m + 4, 1);
    }
    if (ja < NKT) { stA(ab2, ja, 0); stA(ab2, ja, 1); }
    BAR();
    __builtin_amdgcn_s_setprio(1);
#pragma unroll
    for (int ks = 0; ks < 2; ++ks)
#pragma unroll
      for (int m = 0; m < 4; ++m)
#pragma unroll
        for (int n = 0; n < 2; ++n)
          acc[m + 4][n] = MFMA(aF[m][ks], bF[n][ks], acc[m + 4][n]);
    __builtin_amdgcn_s_setprio(0);
    BAR();

    // ---- phase 3 ----
    if (ja < NKT) { stA(ab2, ja, 2); stA(ab2, ja, 3); }
    BAR();
    __builtin_amdgcn_s_setprio(1);
#pragma unroll
    for (int ks = 0; ks < 2; ++ks)
#pragma unroll
      for (int m = 0; m < 4; ++m)
#pragma unroll
        for (int n = 2; n < 4; ++n)
          acc[m + 4][n] = MFMA(aF[m][ks], bF[n][ks], acc[m + 4][n]);
    __builtin_amdgcn_s_setprio(0);
    if (ja < NKT)
      asm volatile("s_waitcnt vmcnt(4)" ::: "memory");
    else if (jn < NKT)
      asm volatile("s_waitcnt vmcnt(0)" ::: "memory");
    BAR();
  }

  if (BF16OUT) {
    // ---- LDS-restaged coalesced bf16 epilogue (2 halves of 128 rows) ----
    char* const LT = (char*)ldsq;  // 64 KB restage tile [128][512B]
#pragma unroll
    for (int h = 0; h < 2; ++h) {
      if (wr == h) {
#pragma unroll
        for (int n = 0; n < 4; ++n) {
          const int col = wc * 64 + n * 16 + rA;
          const float bv = bias[bcol + col];
#pragma unroll
          for (int m = 0; m < 8; ++m)
#pragma unroll
            for (int r = 0; r < 4; ++r) {
              const int R = m * 16 + (lane >> 4) * 4 + r;
              float v = acc[m][n][r] + bv;
              v = v > 0.f ? v : 0.f;
              *(ushort*)(LT + R * 512 + ((col * 2) ^ ((R & 7) << 4))) = f2bf(v);
            }
        }
      }
      __syncthreads();
#pragma unroll
      for (int it = 0; it < 8; ++it) {
        const int idx = it * 8192 + tid * 16;
        const int R = idx >> 9, cb = idx & 511;
        uint4 v = *(const uint4*)(LT + R * 512 + (cb ^ ((R & 7) << 4)));
        *(uint4*)((char*)Cout + (size_t)(brow + h * 128 + R) * (OSTR * 2) +
                  bcol * 2 + cb) = v;
      }
      if (h == 0) __syncthreads();
    }
  } else {
    // ---- f32 epilogue (64B/16-lane lines, already coalesced) ----
#pragma unroll
    for (int n = 0; n < 4; ++n) {
      const int col = bcol + wc * 64 + n * 16 + rA;
      const float bv = bias[col];
#pragma unroll
      for (int m = 0; m < 8; ++m) {
#pragma unroll
        for (int r = 0; r < 4; ++r) {
          const int row = brow + wr * 128 + m * 16 + (lane >> 4) * 4 + r;
          float v = acc[m][n][r] + bv;
          v = v > 0.f ? v : 0.f;
          ((float*)Cout)[(size_t)row * OSTR + col] = v;
        }
      }
    }
  }
}

// ---------------- GEMM1 fallback (fused conversion, round-1 proven) ----------------
__global__ __launch_bounds__(256, 2) void gemm1_fused(
    const float* __restrict__ x, const ushort* __restrict__ w1p,
    const float* __restrict__ bias1, ushort* __restrict__ h1) {
  __shared__ ushort As[128 * 32];
  __shared__ ushort Bs[128 * 32];
  const int tid = threadIdx.x;
  const int lane = tid & 63, wid = tid >> 6;
  const int wr = wid >> 1, wc = wid & 1;
  const int brow = blockIdx.x * 128;
  const int bcol = blockIdx.y * 128;
  f32x4 acc[4][4] = {};
  const int arow = tid >> 1;
  const int acol0 = (tid & 1) * 16;
  const float* xrow = x + (size_t)(brow + arow) * IN_CH;
  for (int kt = 0; kt < 26; ++kt) {
    const int k0 = kt * 32;
#pragma unroll
    for (int c = 0; c < 2; ++c) {
      int idx16 = (wid * 2 + c) * 64 + lane;
      int row = idx16 >> 2, chunk = idx16 & 3;
      glds16(w1p + (size_t)(bcol + row) * KPAD + k0 + chunk * 8,
             (char*)Bs + (wid * 2 + c) * 1024);
    }
    union { ushort u[16]; uint4 q[2]; } pk;
    if (kt < 24) {
      const float* p = xrow + k0 + acol0;
#pragma unroll
      for (int j = 0; j < 8; ++j) {
        float2 v = *(const float2*)(p + j * 2);
        pk.u[j * 2] = f2bf(v.x);
        pk.u[j * 2 + 1] = f2bf(v.y);
      }
    } else {
#pragma unroll
      for (int j = 0; j < 16; ++j) {
        int col = k0 + acol0 + j;
        pk.u[j] = f2bf(col < IN_CH ? xrow[col] : 0.f);
      }
    }
    *(uint4*)&As[arow * 32 + acol0] = pk.q[0];
    *(uint4*)&As[arow * 32 + acol0 + 8] = pk.q[1];
    __syncthreads();
    const int kb = (lane >> 4) * 8, rA = lane & 15;
    short8 af[4], bfrag[4];
#pragma unroll
    for (int m = 0; m < 4; ++m)
      af[m] = *(const short8*)&As[(wr * 64 + m * 16 + rA) * 32 + kb];
#pragma unroll
    for (int n = 0; n < 4; ++n)
      bfrag[n] = *(const short8*)&Bs[(wc * 64 + n * 16 + rA) * 32 + kb];
#pragma unroll
    for (int m = 0; m < 4; ++m)
#pragma unroll
      for (int n = 0; n < 4; ++n)
        acc[m][n] = MFMA(af[m], bfrag[n], acc[m][n]);
    __syncthreads();
  }
  const int orow0 = brow + wr * 64;
  const int ocol0 = bcol + wc * 64;
#pragma unroll
  for (int n = 0; n < 4; ++n) {
    int col = ocol0 + n * 16 + (lane & 15);
    float bv = bias1[col];
#pragma unroll
    for (int m = 0; m < 4; ++m)
#pragma unroll
      for (int r = 0; r < 4; ++r) {
        int row = orow0 + m * 16 + (lane >> 4) * 4 + r;
        float v = acc[m][n][r] + bv;
        v = v > 0.f ? v : 0.f;
        h1[(size_t)row * Z1C + col] = f2bf(v);
      }
  }
}

extern "C" void kernel_launch(void* const* d_in, const int* in_sizes, int n_in,
                              void* d_out, int out_size, void* d_ws, size_t ws_size,
                              hipStream_t stream) {
  (void)in_sizes; (void)n_in; (void)out_size;
  const float* x   = (const float*)d_in[0];
  const float* W1  = (const float*)d_in[1];
  const float* b1  = (const float*)d_in[2];
  const float* Wc1 = (const float*)d_in[3];
  const float* bc1 = (const float*)d_in[4];
  const float* W2  = (const float*)d_in[5];
  const float* b2  = (const float*)d_in[6];
  const float* Wc2 = (const float*)d_in[7];
  const float* bc2 = (const float*)d_in[8];
  const float* MW0 = (const float*)d_in[9];
  const float* MW1 = (const float*)d_in[10];

  char* ws = (char*)d_ws;
  ushort* w1p   = (ushort*)ws;                   // 1024*832*2 = 1,703,936
  ushort* w2m   = (ushort*)(ws + 1703936);       //  512*1024*2 = 1,048,576
  float*  bias1 = (float*)(ws + 2752512);        // 4096
  float*  bias2 = (float*)(ws + 2756608);        // 2048
  ushort* xb    = (ushort*)(ws + 2758656);       // 32768*832*2 = 54,525,952
  const size_t WS_NEED = 2758656ull + 54525952ull;
  const int do_x = (ws_size >= WS_NEED) ? 1 : 0;

  ushort* h1 = (ushort*)d_out;   // 32768x1024 bf16 aliases 32768x512 f32
  float*  out = (float*)d_out;

  prepx<<<3584, 256, 0, stream>>>(W1, b1, Wc1, bc1, MW0, w1p, bias1,
                                  W2, b2, Wc2, bc2, MW1, w2m, bias2,
                                  x, xb, do_x);

  if (do_x) {
    // M=32768 (128 row blocks) x N=1024 (4 col blocks), K=832 (13 tiles)
    gemmT<KPAD, 13, 4, Z1C, true><<<512, 512, 0, stream>>>(xb, w1p, bias1, h1);
  } else {
    gemm1_fused<<<dim3(256, 8), 256, 0, stream>>>(x, w1p, bias1, h1);
  }
  // M=32768 (128 row blocks) x N=512 (2 col blocks), K=1024 (16 tiles)
  gemmT<Z1C, 16, 2, OUT_C, false><<<256, 512, 0, stream>>>(h1, w2m, bias2, out);
}